// Round 1
// baseline (212.980 us; speedup 1.0000x reference)
//
#include <hip/hip_runtime.h>

// NeRF compositing: one WAVE (64 lanes) per ray, 128 samples => 2 samples/lane.
// Fully coalesced float2 loads, wave-level shfl_up scan for the transmittance
// cumprod, shfl_xor butterfly for the weighted color/depth sums.

#define SAMPLES 128

__global__ __launch_bounds__(256) void raymarch_composite(
    const float* __restrict__ sigma,   // [N, S]
    const float* __restrict__ rgb,     // [N, S, 3]
    const float* __restrict__ dists,   // [N, S]
    const float* __restrict__ zvals,   // [N, S]
    const float* __restrict__ bg,      // [N, 3]
    float* __restrict__ out,           // [N, 4]  (r,g,b,depth)
    int n_rays)
{
    const int lane = threadIdx.x & 63;
    const int wave = threadIdx.x >> 6;
    const int ray  = blockIdx.x * (blockDim.x >> 6) + wave;
    if (ray >= n_rays) return;

    const size_t base = (size_t)ray * SAMPLES;

    // lane handles samples s0 = 2*lane, s1 = 2*lane+1  (contiguous across wave)
    const float2 sg = *reinterpret_cast<const float2*>(sigma + base + 2 * lane);
    const float2 dt = *reinterpret_cast<const float2*>(dists + base + 2 * lane);
    const float2 zv = *reinterpret_cast<const float2*>(zvals + base + 2 * lane);

    const float* rgbp = rgb + base * 3 + 6 * lane;   // 6 floats per lane
    const float2 c01 = *reinterpret_cast<const float2*>(rgbp + 0); // r0 g0
    const float2 c23 = *reinterpret_cast<const float2*>(rgbp + 2); // b0 r1
    const float2 c45 = *reinterpret_cast<const float2*>(rgbp + 4); // g1 b1

    // alpha = 1 - exp(-relu(sigma)*dist); factor = 1 - alpha + 1e-10  (ref op order)
    const float eps = 1e-10f;
    const float tau0 = fmaxf(sg.x, 0.0f) * dt.x;
    const float tau1 = fmaxf(sg.y, 0.0f) * dt.y;
    const float alpha0 = 1.0f - expf(-tau0);
    const float alpha1 = 1.0f - expf(-tau1);
    const float f0 = 1.0f - alpha0 + eps;
    const float f1 = 1.0f - alpha1 + eps;

    // Inclusive scan (across lanes) of per-lane factor product p = f0*f1.
    float scan = f0 * f1;
    #pragma unroll
    for (int off = 1; off < 64; off <<= 1) {
        const float up = __shfl_up(scan, off);
        scan *= (lane >= off) ? up : 1.0f;
    }
    // Exclusive prefix = transmittance before this lane's first sample.
    float excl = __shfl_up(scan, 1);
    if (lane == 0) excl = 1.0f;
    const float no_hit = __shfl(scan, 63);   // product over all samples

    const float w0 = alpha0 * excl;          // weight for sample 2*lane
    const float w1 = alpha1 * (excl * f0);   // weight for sample 2*lane+1

    // Per-lane partial sums for color and depth.
    float r = w0 * c01.x + w1 * c23.y;
    float g = w0 * c01.y + w1 * c45.x;
    float b = w0 * c23.x + w1 * c45.y;
    float d = w0 * zv.x  + w1 * zv.y;

    // Wave-wide butterfly reduction (all lanes end with the total).
    #pragma unroll
    for (int off = 32; off >= 1; off >>= 1) {
        r += __shfl_xor(r, off);
        g += __shfl_xor(g, off);
        b += __shfl_xor(b, off);
        d += __shfl_xor(d, off);
    }

    if (lane == 0) {
        const float bgr = bg[ray * 3 + 0];
        const float bgg = bg[ray * 3 + 1];
        const float bgb = bg[ray * 3 + 2];
        float4 o;
        o.x = r + no_hit * bgr;
        o.y = g + no_hit * bgg;
        o.z = b + no_hit * bgb;
        o.w = d;
        *reinterpret_cast<float4*>(out + (size_t)ray * 4) = o;
    }
}

extern "C" void kernel_launch(void* const* d_in, const int* in_sizes, int n_in,
                              void* d_out, int out_size, void* d_ws, size_t ws_size,
                              hipStream_t stream) {
    const float* sigma = (const float*)d_in[0];
    const float* rgb   = (const float*)d_in[1];
    const float* dists = (const float*)d_in[2];
    const float* zvals = (const float*)d_in[3];
    const float* bg    = (const float*)d_in[4];
    float* out = (float*)d_out;

    const int n_rays = in_sizes[0] / SAMPLES;   // 65536
    const int waves_per_block = 256 / 64;       // 4 rays per block
    const int grid = (n_rays + waves_per_block - 1) / waves_per_block;

    raymarch_composite<<<grid, 256, 0, stream>>>(sigma, rgb, dists, zvals, bg,
                                                 out, n_rays);
}